// Round 4
// baseline (781.784 us; speedup 1.0000x reference)
//
#include <hip/hip_runtime.h>
#include <math.h>

// EquiAttention, MI355X. Single-pass streaming over messages (256 MB), fused
// masked-softmax + weighted-sum + L2-norm scaling + output projection.
// R4 = R3 with compile fix: __builtin_nontemporal_load needs a clang
// ext_vector_type, not HIP's float4 class. Depth-3 register pipeline
// (15 outstanding 1KB wave-loads), 33-step padded trip (bias=-inf dummy),
// messages loaded non-temporally.

namespace {

constexpr int kB   = 4;
constexpr int kNQ  = 512;
constexpr int kNKV = 512;
constexpr int kD   = 64;
constexpr int kQT  = 2;          // q rows per block
constexpr float kNegInf = -1e10f;

typedef float vfloat4 __attribute__((ext_vector_type(4)));

// proj[b,k,c,e] = sum_d v[b,k,c,d] * w[e,d].  4 rows of 64 per block.
__global__ __launch_bounds__(256)
void proj_kernel(const float* __restrict__ v, const float* __restrict__ w,
                 float* __restrict__ out) {
  __shared__ float wt[64 * 65];   // wt[d*65+e] = w[e*64+d]  (+1 pad)
  __shared__ float rows[256];
  const int t = threadIdx.x;
  for (int i = t; i < 4096; i += 256) {
    wt[(i & 63) * 65 + (i >> 6)] = w[i];
  }
  const long rowbase = (long)blockIdx.x * 4;
  rows[t] = v[rowbase * 64 + t];
  __syncthreads();
  const int r = t >> 6;
  const int e = t & 63;
  float acc = 0.f;
#pragma unroll
  for (int d = 0; d < 64; ++d) {
    acc = fmaf(rows[r * 64 + d], wt[d * 65 + e], acc);
  }
  out[rowbase * 64 + t] = acc;
}

struct Stage {
  vfloat4 m0, m1;      // messages for q0, q0+1 (4 d-values each)
  vfloat4 p0, p1, p2;  // proj_equi c=0,1,2
  float   b0, b1;      // mask bias per q (from LDS)
};

__device__ __forceinline__ void issue(Stage& S,
    const float* __restrict__ mp0, const float* __restrict__ mp1,
    const float* __restrict__ pp,
    const float* bp0, const float* bp1, int it) {
  const int itc = it < 32 ? it : 31;   // dummy steps re-read step 31 (L1 hit)
  const int mo = itc * 4 * kD;         // msg advances 4 rows of 64 per step
  const int po = itc * 4 * 3 * kD;     // proj advances 4 rows of 3*64 per step
  S.p0 = *(const vfloat4*)(pp + po);
  S.p1 = *(const vfloat4*)(pp + po + kD);
  S.p2 = *(const vfloat4*)(pp + po + 2 * kD);
  S.m0 = __builtin_nontemporal_load((const vfloat4*)(mp0 + mo));
  S.m1 = __builtin_nontemporal_load((const vfloat4*)(mp1 + mo));
  // dummy steps get bias=-inf -> exp()==0 -> contribute nothing
  S.b0 = it < 32 ? bp0[itc * 4] : kNegInf;
  S.b1 = it < 32 ? bp1[itc * 4] : kNegInf;
}

// One block = (b, q0..q0+1). Wave w owns k in [128w,128w+128); lane layout:
// ksub = lane>>4, d0 = (lane&15)*4 -> each wave msg load = 1 KB contiguous.
__global__ __launch_bounds__(256, 4)
void attn_kernel(const float* __restrict__ msg, const int* __restrict__ adj,
                 const float* __restrict__ proj, const float* __restrict__ wattn,
                 float* __restrict__ out) {
  __shared__ float wt[64 * 65];        // w_attn transposed + pad
  __shared__ float bias[kQT * kNKV];   // 0 or -1e10 per (q,k)
  __shared__ float red[4][kQT][64][5]; // per-wave partials: S, SQ, A0, A1, A2
  __shared__ float afin[kQT][3][64];   // attn_out * weights, pre-projection

  const int t   = threadIdx.x;
  const int blk = blockIdx.x;
  const int b   = blk / (kNQ / kQT);
  const int q0  = (blk % (kNQ / kQT)) * kQT;

  for (int i = t; i < 4096; i += 256) {
    wt[(i & 63) * 65 + (i >> 6)] = wattn[i];
  }
  for (int i = t; i < kQT * kNKV; i += 256) {
    const int q = i >> 9;   // kQT == 2
    const int k = i & (kNKV - 1);
    bias[i] = (adj[((long)(b * kNQ + q0 + q)) * kNKV + k] > 0) ? 0.f : kNegInf;
  }
  __syncthreads();

  const int wave = t >> 6;
  const int lane = t & 63;
  const int ksub = lane >> 4;
  const int d0   = (lane & 15) << 2;
  const int wbase = wave * 128;

  const float* mp0 = msg + ((long)(b * kNQ + q0) * kNKV + wbase + ksub) * kD + d0;
  const float* mp1 = mp0 + (long)kNKV * kD;
  const float* pp  = proj + ((long)b * kNKV + wbase + ksub) * 3 * kD + d0;
  const float* bp0 = &bias[wbase + ksub];
  const float* bp1 = &bias[kNKV + wbase + ksub];

  float s[kQT][4]  = {};
  float sq[kQT][4] = {};
  float a0[kQT][4] = {};
  float a1[kQT][4] = {};
  float a2[kQT][4] = {};

  auto consume = [&](const Stage& S) {
    const float e00 = __expf(S.m0.x + S.b0);
    const float e01 = __expf(S.m0.y + S.b0);
    const float e02 = __expf(S.m0.z + S.b0);
    const float e03 = __expf(S.m0.w + S.b0);
    const float e10 = __expf(S.m1.x + S.b1);
    const float e11 = __expf(S.m1.y + S.b1);
    const float e12 = __expf(S.m1.z + S.b1);
    const float e13 = __expf(S.m1.w + S.b1);
    s[0][0] += e00; s[0][1] += e01; s[0][2] += e02; s[0][3] += e03;
    s[1][0] += e10; s[1][1] += e11; s[1][2] += e12; s[1][3] += e13;
    sq[0][0] = fmaf(e00, e00, sq[0][0]);
    sq[0][1] = fmaf(e01, e01, sq[0][1]);
    sq[0][2] = fmaf(e02, e02, sq[0][2]);
    sq[0][3] = fmaf(e03, e03, sq[0][3]);
    sq[1][0] = fmaf(e10, e10, sq[1][0]);
    sq[1][1] = fmaf(e11, e11, sq[1][1]);
    sq[1][2] = fmaf(e12, e12, sq[1][2]);
    sq[1][3] = fmaf(e13, e13, sq[1][3]);
    a0[0][0] = fmaf(e00, S.p0.x, a0[0][0]);
    a0[0][1] = fmaf(e01, S.p0.y, a0[0][1]);
    a0[0][2] = fmaf(e02, S.p0.z, a0[0][2]);
    a0[0][3] = fmaf(e03, S.p0.w, a0[0][3]);
    a0[1][0] = fmaf(e10, S.p0.x, a0[1][0]);
    a0[1][1] = fmaf(e11, S.p0.y, a0[1][1]);
    a0[1][2] = fmaf(e12, S.p0.z, a0[1][2]);
    a0[1][3] = fmaf(e13, S.p0.w, a0[1][3]);
    a1[0][0] = fmaf(e00, S.p1.x, a1[0][0]);
    a1[0][1] = fmaf(e01, S.p1.y, a1[0][1]);
    a1[0][2] = fmaf(e02, S.p1.z, a1[0][2]);
    a1[0][3] = fmaf(e03, S.p1.w, a1[0][3]);
    a1[1][0] = fmaf(e10, S.p1.x, a1[1][0]);
    a1[1][1] = fmaf(e11, S.p1.y, a1[1][1]);
    a1[1][2] = fmaf(e12, S.p1.z, a1[1][2]);
    a1[1][3] = fmaf(e13, S.p1.w, a1[1][3]);
    a2[0][0] = fmaf(e00, S.p2.x, a2[0][0]);
    a2[0][1] = fmaf(e01, S.p2.y, a2[0][1]);
    a2[0][2] = fmaf(e02, S.p2.z, a2[0][2]);
    a2[0][3] = fmaf(e03, S.p2.w, a2[0][3]);
    a2[1][0] = fmaf(e10, S.p2.x, a2[1][0]);
    a2[1][1] = fmaf(e11, S.p2.y, a2[1][1]);
    a2[1][2] = fmaf(e12, S.p2.z, a2[1][2]);
    a2[1][3] = fmaf(e13, S.p2.w, a2[1][3]);
  };

  // Depth-3 software pipeline over 33 steps (step 32 is a bias=-inf dummy).
  // Ring of named stages; 11 groups of 3 keeps all indexing static.
  Stage s0_, s1_, s2_;
  issue(s0_, mp0, mp1, pp, bp0, bp1, 0);
  issue(s1_, mp0, mp1, pp, bp0, bp1, 1);
  issue(s2_, mp0, mp1, pp, bp0, bp1, 2);
#pragma unroll
  for (int g = 0; g < 11; ++g) {
    const int base = g * 3;
    consume(s0_); issue(s0_, mp0, mp1, pp, bp0, bp1, base + 3);
    consume(s1_); issue(s1_, mp0, mp1, pp, bp0, bp1, base + 4);
    consume(s2_); issue(s2_, mp0, mp1, pp, bp0, bp1, base + 5);
  }
  // consumed steps 0..32 (32 real + 1 dummy); trailing issued stages unused.

  // Reduce across the 4 k-subgroups within the wave (lanes xor 16, xor 32).
#pragma unroll
  for (int j = 0; j < kQT; ++j) {
#pragma unroll
    for (int i = 0; i < 4; ++i) {
      s[j][i]  += __shfl_xor(s[j][i], 16, 64);
      s[j][i]  += __shfl_xor(s[j][i], 32, 64);
      sq[j][i] += __shfl_xor(sq[j][i], 16, 64);
      sq[j][i] += __shfl_xor(sq[j][i], 32, 64);
      a0[j][i] += __shfl_xor(a0[j][i], 16, 64);
      a0[j][i] += __shfl_xor(a0[j][i], 32, 64);
      a1[j][i] += __shfl_xor(a1[j][i], 16, 64);
      a1[j][i] += __shfl_xor(a1[j][i], 32, 64);
      a2[j][i] += __shfl_xor(a2[j][i], 16, 64);
      a2[j][i] += __shfl_xor(a2[j][i], 32, 64);
    }
  }
  if (lane < 16) {
#pragma unroll
    for (int j = 0; j < kQT; ++j) {
#pragma unroll
      for (int i = 0; i < 4; ++i) {
        const int d = d0 + i;
        red[wave][j][d][0] = s[j][i];
        red[wave][j][d][1] = sq[j][i];
        red[wave][j][d][2] = a0[j][i];
        red[wave][j][d][3] = a1[j][i];
        red[wave][j][d][4] = a2[j][i];
      }
    }
  }
  __syncthreads();

  // Cross-wave reduce + fold normalization and L2-norm weight:
  // attn_out*weights = A_c * sqrt(SQ) / S^2
  if (t < kQT * 64) {
    const int q = t >> 6;
    const int d = t & 63;
    float S = 0.f, SQ = 0.f, A0 = 0.f, A1 = 0.f, A2 = 0.f;
#pragma unroll
    for (int w = 0; w < 4; ++w) {
      S  += red[w][q][d][0];
      SQ += red[w][q][d][1];
      A0 += red[w][q][d][2];
      A1 += red[w][q][d][3];
      A2 += red[w][q][d][4];
    }
    const float inv = 1.f / S;
    const float wgt = sqrtf(SQ) * inv * inv;
    afin[q][0][d] = A0 * wgt;
    afin[q][1][d] = A1 * wgt;
    afin[q][2][d] = A2 * wgt;
  }
  __syncthreads();

  // out[b,q,c,e] = sum_d afin[q][c][d] * w_attn[e][d]
  for (int o = t; o < kQT * 3 * 64; o += 256) {
    const int q = o / 192;
    const int c = (o % 192) / 64;
    const int e = o & 63;
    float acc = 0.f;
#pragma unroll
    for (int d = 0; d < 64; ++d) {
      acc = fmaf(afin[q][c][d], wt[d * 65 + e], acc);
    }
    out[(((long)(b * kNQ + q0 + q)) * 3 + c) * kD + e] = acc;
  }
}

}  // namespace

extern "C" void kernel_launch(void* const* d_in, const int* in_sizes, int n_in,
                              void* d_out, int out_size, void* d_ws, size_t ws_size,
                              hipStream_t stream) {
  const float* v_equi   = (const float*)d_in[0];
  const float* messages = (const float*)d_in[1];
  const int*   adj      = (const int*)d_in[2];
  const float* w_coord  = (const float*)d_in[3];
  const float* w_attn   = (const float*)d_in[4];
  float* outp = (float*)d_out;
  float* projw = (float*)d_ws;  // B*NKV*3*D floats = 1.5 MB

  proj_kernel<<<kB * kNKV * 3 / 4, 256, 0, stream>>>(v_equi, w_coord, projw);
  attn_kernel<<<kB * (kNQ / kQT), 256, 0, stream>>>(messages, adj, projw, w_attn, outp);
}

// Round 5
// 377.802 us; speedup vs baseline: 2.0693x; 2.0693x over previous
//
#include <hip/hip_runtime.h>
#include <math.h>

// EquiAttention, MI355X. Single-pass streaming over messages (256 MB), fused
// masked-softmax + weighted-sum + L2-norm scaling + output projection.
// R5: LDS double-buffer for the message stream via global_load_lds width=16
// (m97 pattern) -- deep prefetch with ZERO VGPR cost (R4's register ring
// spilled to scratch: WRITE_SIZE 1.1 GB). proj stays as depth-2 register
// prefetch (L2-hot). Message ring (16 KB) aliases the epilogue wt/red/afin
// LDS region; wt is transpose-loaded after the k-loop behind a barrier.

namespace {

constexpr int kB   = 4;
constexpr int kNQ  = 512;
constexpr int kNKV = 512;
constexpr int kD   = 64;
constexpr int kQT  = 2;          // q rows per block
constexpr float kNegInf = -1e10f;

typedef float vfloat4 __attribute__((ext_vector_type(4)));

typedef const __attribute__((address_space(1))) void* gas_ptr;
typedef __attribute__((address_space(3))) void* las_ptr;

__device__ __forceinline__ void gl_lds16(const float* g, float* l) {
  __builtin_amdgcn_global_load_lds((gas_ptr)(const void*)g, (las_ptr)(void*)l,
                                   16, 0, 0);
}

// proj[b,k,c,e] = sum_d v[b,k,c,d] * w[e,d].  4 rows of 64 per block.
__global__ __launch_bounds__(256)
void proj_kernel(const float* __restrict__ v, const float* __restrict__ w,
                 float* __restrict__ out) {
  __shared__ float wt[64 * 65];   // wt[d*65+e] = w[e*64+d]  (+1 pad)
  __shared__ float rows[256];
  const int t = threadIdx.x;
  for (int i = t; i < 4096; i += 256) {
    wt[(i & 63) * 65 + (i >> 6)] = w[i];
  }
  const long rowbase = (long)blockIdx.x * 4;
  rows[t] = v[rowbase * 64 + t];
  __syncthreads();
  const int r = t >> 6;
  const int e = t & 63;
  float acc = 0.f;
#pragma unroll
  for (int d = 0; d < 64; ++d) {
    acc = fmaf(rows[r * 64 + d], wt[d * 65 + e], acc);
  }
  out[rowbase * 64 + t] = acc;
}

// One block = (b, q0..q0+1). Wave w owns k in [128w,128w+128); 32 steps of
// 4 k-rows. Per step each wave stages 2x1KB of messages (q0,q1) into the LDS
// ring with global_load_lds; __syncthreads() at step top drains vmcnt.
__global__ __launch_bounds__(256, 4)
void attn_kernel(const float* __restrict__ msg, const int* __restrict__ adj,
                 const float* __restrict__ proj, const float* __restrict__ wattn,
                 float* __restrict__ out) {
  // smem aliasing:
  //   [0..4095]    message ring  float[2][4][2][256] (k-loop only)
  //   [0..4159]    wt (w_attn transposed, +1 pad)    (epilogue only)
  //   [4160..6719] red [4][2][64][5]                 (epilogue only)
  //   [6720..7103] afin [2][3][64]                   (epilogue only)
  __shared__ float smem[7104];
  __shared__ float bias[kQT * kNKV];   // 0 or -1e10 per (q,k)
  float* const ring = smem;
  float* const wt   = smem;
  float* const red  = smem + 4160;
  float* const afin = smem + 6720;

  const int t   = threadIdx.x;
  const int blk = blockIdx.x;
  const int b   = blk / (kNQ / kQT);
  const int q0  = (blk % (kNQ / kQT)) * kQT;

  for (int i = t; i < kQT * kNKV; i += 256) {
    const int q = i >> 9;   // kQT == 2
    const int k = i & (kNKV - 1);
    bias[i] = (adj[((long)(b * kNQ + q0 + q)) * kNKV + k] > 0) ? 0.f : kNegInf;
  }

  const int wave = t >> 6;
  const int lane = t & 63;
  const int ksub = lane >> 4;
  const int d0   = (lane & 15) << 2;
  const int wbase = wave * 128;

  // Per-lane global sources (lane term = lane*4 floats = lane*16 bytes).
  const float* gm0 = msg + ((long)(b * kNQ + q0) * kNKV + wbase) * kD + lane * 4;
  const float* gm1 = gm0 + (long)kNKV * kD;
  // Per-lane LDS destinations inside this wave's ring chunk.
  float* const l0a = ring + ((0 * 4 + wave) * 2 + 0) * 256 + lane * 4;
  float* const l1a = ring + ((0 * 4 + wave) * 2 + 1) * 256 + lane * 4;
  float* const l0b = ring + ((1 * 4 + wave) * 2 + 0) * 256 + lane * 4;
  float* const l1b = ring + ((1 * 4 + wave) * 2 + 1) * 256 + lane * 4;
  // Consume pointers (per lane): this wave's chunk, row ksub, cols d0..d0+3.
  const float* c0a = ring + ((0 * 4 + wave) * 2 + 0) * 256 + ksub * 64 + d0;
  const float* c1a = ring + ((0 * 4 + wave) * 2 + 1) * 256 + ksub * 64 + d0;
  const float* c0b = ring + ((1 * 4 + wave) * 2 + 0) * 256 + ksub * 64 + d0;
  const float* c1b = ring + ((1 * 4 + wave) * 2 + 1) * 256 + ksub * 64 + d0;

  const float* pp  = proj + ((long)b * kNKV + wbase + ksub) * 3 * kD + d0;
  const float* bp0 = &bias[wbase + ksub];
  const float* bp1 = &bias[kNKV + wbase + ksub];

  float s[kQT][4]  = {};
  float sq[kQT][4] = {};
  float a0[kQT][4] = {};
  float a1[kQT][4] = {};
  float a2[kQT][4] = {};

  auto consume = [&](const float* cm0, const float* cm1, int it,
                     const vfloat4& P0, const vfloat4& P1, const vfloat4& P2) {
    const vfloat4 m0 = *(const vfloat4*)cm0;
    const vfloat4 m1 = *(const vfloat4*)cm1;
    const float b0v = bp0[it * 4];
    const float b1v = bp1[it * 4];
    const float e00 = __expf(m0.x + b0v);
    const float e01 = __expf(m0.y + b0v);
    const float e02 = __expf(m0.z + b0v);
    const float e03 = __expf(m0.w + b0v);
    const float e10 = __expf(m1.x + b1v);
    const float e11 = __expf(m1.y + b1v);
    const float e12 = __expf(m1.z + b1v);
    const float e13 = __expf(m1.w + b1v);
    s[0][0] += e00; s[0][1] += e01; s[0][2] += e02; s[0][3] += e03;
    s[1][0] += e10; s[1][1] += e11; s[1][2] += e12; s[1][3] += e13;
    sq[0][0] = fmaf(e00, e00, sq[0][0]);
    sq[0][1] = fmaf(e01, e01, sq[0][1]);
    sq[0][2] = fmaf(e02, e02, sq[0][2]);
    sq[0][3] = fmaf(e03, e03, sq[0][3]);
    sq[1][0] = fmaf(e10, e10, sq[1][0]);
    sq[1][1] = fmaf(e11, e11, sq[1][1]);
    sq[1][2] = fmaf(e12, e12, sq[1][2]);
    sq[1][3] = fmaf(e13, e13, sq[1][3]);
    a0[0][0] = fmaf(e00, P0.x, a0[0][0]);
    a0[0][1] = fmaf(e01, P0.y, a0[0][1]);
    a0[0][2] = fmaf(e02, P0.z, a0[0][2]);
    a0[0][3] = fmaf(e03, P0.w, a0[0][3]);
    a0[1][0] = fmaf(e10, P0.x, a0[1][0]);
    a0[1][1] = fmaf(e11, P0.y, a0[1][1]);
    a0[1][2] = fmaf(e12, P0.z, a0[1][2]);
    a0[1][3] = fmaf(e13, P0.w, a0[1][3]);
    a1[0][0] = fmaf(e00, P1.x, a1[0][0]);
    a1[0][1] = fmaf(e01, P1.y, a1[0][1]);
    a1[0][2] = fmaf(e02, P1.z, a1[0][2]);
    a1[0][3] = fmaf(e03, P1.w, a1[0][3]);
    a1[1][0] = fmaf(e10, P1.x, a1[1][0]);
    a1[1][1] = fmaf(e11, P1.y, a1[1][1]);
    a1[1][2] = fmaf(e12, P1.z, a1[1][2]);
    a1[1][3] = fmaf(e13, P1.w, a1[1][3]);
    a2[0][0] = fmaf(e00, P2.x, a2[0][0]);
    a2[0][1] = fmaf(e01, P2.y, a2[0][1]);
    a2[0][2] = fmaf(e02, P2.z, a2[0][2]);
    a2[0][3] = fmaf(e03, P2.w, a2[0][3]);
    a2[1][0] = fmaf(e10, P2.x, a2[1][0]);
    a2[1][1] = fmaf(e11, P2.y, a2[1][1]);
    a2[1][2] = fmaf(e12, P2.z, a2[1][2]);
    a2[1][3] = fmaf(e13, P2.w, a2[1][3]);
  };

  // Prologue: stage step 0 into buffer A; prefetch proj step 0.
  gl_lds16(gm0, l0a);
  gl_lds16(gm1, l1a);
  vfloat4 PA0 = *(const vfloat4*)(pp + 0);
  vfloat4 PA1 = *(const vfloat4*)(pp + kD);
  vfloat4 PA2 = *(const vfloat4*)(pp + 2 * kD);
  vfloat4 PB0, PB1, PB2;

  for (int it = 0; it < 32; it += 2) {
    // --- even step: consume A, stage B ---
    __syncthreads();                       // A's staging drained
    {
      const int nx = it + 1;
      gl_lds16(gm0 + nx * 256, l0b);
      gl_lds16(gm1 + nx * 256, l1b);
      PB0 = *(const vfloat4*)(pp + nx * 768);
      PB1 = *(const vfloat4*)(pp + nx * 768 + kD);
      PB2 = *(const vfloat4*)(pp + nx * 768 + 2 * kD);
    }
    consume(c0a, c1a, it, PA0, PA1, PA2);
    // --- odd step: consume B, stage A ---
    __syncthreads();                       // B's staging drained
    if (it + 2 < 32) {
      const int nx = it + 2;
      gl_lds16(gm0 + nx * 256, l0a);
      gl_lds16(gm1 + nx * 256, l1a);
      PA0 = *(const vfloat4*)(pp + nx * 768);
      PA1 = *(const vfloat4*)(pp + nx * 768 + kD);
      PA2 = *(const vfloat4*)(pp + nx * 768 + 2 * kD);
    }
    consume(c0b, c1b, it + 1, PB0, PB1, PB2);
  }

  // Reduce across the 4 k-subgroups within the wave (lanes xor 16, xor 32).
#pragma unroll
  for (int j = 0; j < kQT; ++j) {
#pragma unroll
    for (int i = 0; i < 4; ++i) {
      s[j][i]  += __shfl_xor(s[j][i], 16, 64);
      s[j][i]  += __shfl_xor(s[j][i], 32, 64);
      sq[j][i] += __shfl_xor(sq[j][i], 16, 64);
      sq[j][i] += __shfl_xor(sq[j][i], 32, 64);
      a0[j][i] += __shfl_xor(a0[j][i], 16, 64);
      a0[j][i] += __shfl_xor(a0[j][i], 32, 64);
      a1[j][i] += __shfl_xor(a1[j][i], 16, 64);
      a1[j][i] += __shfl_xor(a1[j][i], 32, 64);
      a2[j][i] += __shfl_xor(a2[j][i], 16, 64);
      a2[j][i] += __shfl_xor(a2[j][i], 32, 64);
    }
  }

  __syncthreads();   // all waves done reading the ring; wt may now overwrite it

  // Stage w_attn transposed into wt (aliases the dead ring region).
  for (int i = t; i < 4096; i += 256) {
    wt[(i & 63) * 65 + (i >> 6)] = wattn[i];
  }
  if (lane < 16) {
#pragma unroll
    for (int j = 0; j < kQT; ++j) {
#pragma unroll
      for (int i = 0; i < 4; ++i) {
        const int d = d0 + i;
        float* r = red + ((wave * kQT + j) * 64 + d) * 5;
        r[0] = s[j][i];
        r[1] = sq[j][i];
        r[2] = a0[j][i];
        r[3] = a1[j][i];
        r[4] = a2[j][i];
      }
    }
  }
  __syncthreads();

  // Cross-wave reduce + fold normalization and L2-norm weight:
  // attn_out*weights = A_c * sqrt(SQ) / S^2
  if (t < kQT * 64) {
    const int q = t >> 6;
    const int d = t & 63;
    float S = 0.f, SQ = 0.f, A0 = 0.f, A1 = 0.f, A2 = 0.f;
#pragma unroll
    for (int w = 0; w < 4; ++w) {
      const float* r = red + ((w * kQT + q) * 64 + d) * 5;
      S += r[0]; SQ += r[1]; A0 += r[2]; A1 += r[3]; A2 += r[4];
    }
    const float inv = 1.f / S;
    const float wgt = sqrtf(SQ) * inv * inv;
    afin[(q * 3 + 0) * 64 + d] = A0 * wgt;
    afin[(q * 3 + 1) * 64 + d] = A1 * wgt;
    afin[(q * 3 + 2) * 64 + d] = A2 * wgt;
  }
  __syncthreads();

  // out[b,q,c,e] = sum_d afin[q][c][d] * w_attn[e][d]
  for (int o = t; o < kQT * 3 * 64; o += 256) {
    const int q = o / 192;
    const int c = (o % 192) / 64;
    const int e = o & 63;
    float acc = 0.f;
#pragma unroll
    for (int d = 0; d < 64; ++d) {
      acc = fmaf(afin[(q * 3 + c) * 64 + d], wt[d * 65 + e], acc);
    }
    out[(((long)(b * kNQ + q0 + q)) * 3 + c) * kD + e] = acc;
  }
}

}  // namespace

extern "C" void kernel_launch(void* const* d_in, const int* in_sizes, int n_in,
                              void* d_out, int out_size, void* d_ws, size_t ws_size,
                              hipStream_t stream) {
  const float* v_equi   = (const float*)d_in[0];
  const float* messages = (const float*)d_in[1];
  const int*   adj      = (const int*)d_in[2];
  const float* w_coord  = (const float*)d_in[3];
  const float* w_attn   = (const float*)d_in[4];
  float* outp = (float*)d_out;
  float* projw = (float*)d_ws;  // B*NKV*3*D floats = 1.5 MB

  proj_kernel<<<kB * kNKV * 3 / 4, 256, 0, stream>>>(v_equi, w_coord, projw);
  attn_kernel<<<kB * (kNQ / kQT), 256, 0, stream>>>(messages, adj, projw, w_attn, outp);
}